// Round 2
// baseline (1829.649 us; speedup 1.0000x reference)
//
#include <hip/hip_runtime.h>

#define EMB 128
#define NF  128
#define K_IN 256
#define BM  64
#define KC  32

// ---------------------------------------------------------------------------
// Kernel 1: scatter-add edge embeddings into node accumulator (f32 atomics).
// One thread handles one float4 (4 features) of one edge.
// ---------------------------------------------------------------------------
__global__ __launch_bounds__(256) void scatter_kernel(
    const float* __restrict__ h, const int* __restrict__ dst,
    float* __restrict__ aggr, int E) {
  const long total = (long)E * 32;          // 32 float4 per edge row
  const long stride = (long)gridDim.x * blockDim.x;
  for (long i = (long)blockIdx.x * blockDim.x + threadIdx.x; i < total; i += stride) {
    const long e  = i >> 5;
    const int  c4 = (int)(i & 31);
    float4 v = reinterpret_cast<const float4*>(h)[e * 32 + c4];
    int d = dst[e];
    float* p = aggr + (long)d * EMB + c4 * 4;
    atomicAdd(p + 0, v.x);
    atomicAdd(p + 1, v.y);
    atomicAdd(p + 2, v.z);
    atomicAdd(p + 3, v.w);
  }
}

// ---------------------------------------------------------------------------
// Kernel 2: out = relu([x | aggr] @ W^T + b)
// Block: 256 threads, computes BM=64 rows x 128 cols.
// Thread (rowg = t>>4, colg = t&15) owns 4 rows x 8 cols in registers.
// K staged in KC=32 chunks: qc[64][36] (padded), wt[32][132] (transposed W).
// ---------------------------------------------------------------------------
__global__ __launch_bounds__(256) void gemm_relu_kernel(
    const float* __restrict__ x, const float* __restrict__ aggr,
    const float* __restrict__ W, const float* __restrict__ bias,
    float* __restrict__ out, int N) {
  __shared__ float qc[BM][36];      // 64 rows x 32 k (pad to 36: conflict-light)
  __shared__ float wt[KC][EMB + 4]; // transposed W chunk: wt[kk][col], pad 132

  const int t = threadIdx.x;
  const int row0 = blockIdx.x * BM;
  const int rowg = t >> 4;   // 0..15 -> rows rowg*4 .. rowg*4+3
  const int colg = t & 15;   // 0..15 -> cols colg*8 .. colg*8+7

  float acc[4][8];
#pragma unroll
  for (int i = 0; i < 4; ++i)
#pragma unroll
    for (int j = 0; j < 8; ++j) acc[i][j] = 0.f;

  for (int k0 = 0; k0 < K_IN; k0 += KC) {
    // ---- stage q chunk: rows row0..row0+63, k columns k0..k0+31 ----
    const float* src = (k0 < NF) ? x : aggr;
    const int koff = (k0 < NF) ? k0 : (k0 - NF);
#pragma unroll
    for (int i = 0; i < 2; ++i) {
      int idx = t + i * 256;        // 0..511 (512 float4 = 64 rows * 8 f4)
      int r  = idx >> 3;
      int c4 = idx & 7;
      float4 v = make_float4(0.f, 0.f, 0.f, 0.f);
      if (row0 + r < N)
        v = *reinterpret_cast<const float4*>(src + (long)(row0 + r) * 128 + koff + c4 * 4);
      *reinterpret_cast<float4*>(&qc[r][c4 * 4]) = v;
    }
    // ---- stage W chunk transposed: wt[kk][col] = W[col][k0+kk] ----
#pragma unroll
    for (int i = 0; i < 4; ++i) {
      int idx = t + i * 256;        // 0..1023 (128 cols * 8 f4)
      int col = idx >> 3;
      int c4  = idx & 7;
      float4 v = *reinterpret_cast<const float4*>(W + (long)col * K_IN + k0 + c4 * 4);
      wt[c4 * 4 + 0][col] = v.x;
      wt[c4 * 4 + 1][col] = v.y;
      wt[c4 * 4 + 2][col] = v.z;
      wt[c4 * 4 + 3][col] = v.w;
    }
    __syncthreads();

    // ---- accumulate ----
#pragma unroll
    for (int kk = 0; kk < KC; ++kk) {
      float4 w0 = *reinterpret_cast<const float4*>(&wt[kk][colg * 8]);
      float4 w1 = *reinterpret_cast<const float4*>(&wt[kk][colg * 8 + 4]);
#pragma unroll
      for (int i = 0; i < 4; ++i) {
        float q = qc[(rowg << 2) + i][kk];
        acc[i][0] += q * w0.x;
        acc[i][1] += q * w0.y;
        acc[i][2] += q * w0.z;
        acc[i][3] += q * w0.w;
        acc[i][4] += q * w1.x;
        acc[i][5] += q * w1.y;
        acc[i][6] += q * w1.z;
        acc[i][7] += q * w1.w;
      }
    }
    __syncthreads();
  }

  // ---- epilogue: bias + relu, vectorized store ----
  float4 b0 = *reinterpret_cast<const float4*>(bias + colg * 8);
  float4 b1 = *reinterpret_cast<const float4*>(bias + colg * 8 + 4);
#pragma unroll
  for (int i = 0; i < 4; ++i) {
    int row = row0 + (rowg << 2) + i;
    if (row < N) {
      float4 o0, o1;
      o0.x = fmaxf(acc[i][0] + b0.x, 0.f);
      o0.y = fmaxf(acc[i][1] + b0.y, 0.f);
      o0.z = fmaxf(acc[i][2] + b0.z, 0.f);
      o0.w = fmaxf(acc[i][3] + b0.w, 0.f);
      o1.x = fmaxf(acc[i][4] + b1.x, 0.f);
      o1.y = fmaxf(acc[i][5] + b1.y, 0.f);
      o1.z = fmaxf(acc[i][6] + b1.z, 0.f);
      o1.w = fmaxf(acc[i][7] + b1.w, 0.f);
      float* dst = out + (long)row * EMB + colg * 8;
      *reinterpret_cast<float4*>(dst)     = o0;
      *reinterpret_cast<float4*>(dst + 4) = o1;
    }
  }
}

extern "C" void kernel_launch(void* const* d_in, const int* in_sizes, int n_in,
                              void* d_out, int out_size, void* d_ws, size_t ws_size,
                              hipStream_t stream) {
  const float* h        = (const float*)d_in[0];
  const float* x        = (const float*)d_in[1];
  const int*   edge_dst = (const int*)d_in[2];
  const float* W        = (const float*)d_in[3];
  const float* b        = (const float*)d_in[4];
  float* out = (float*)d_out;

  const int E = in_sizes[2];
  const int N = in_sizes[1] / NF;

  float* aggr = (float*)d_ws;                 // N * EMB floats = 25.6 MB

  hipMemsetAsync(aggr, 0, (size_t)N * EMB * sizeof(float), stream);
  scatter_kernel<<<8192, 256, 0, stream>>>(h, edge_dst, aggr, E);
  gemm_relu_kernel<<<(N + BM - 1) / BM, 256, 0, stream>>>(x, aggr, W, b, out, N);
}